// Round 1
// 1413.052 us; speedup vs baseline: 1.0841x; 1.0841x over previous
//
#include <hip/hip_runtime.h>
#include <hip/hip_fp16.h>

// GNN_6253472383532: dynamic top-k GCN block + BN + relu residual.
// b=16384, n=12, c=512, K(neighbors)=4.
//
// Math rewrite: agg = A @ (x@Vw^T + Vb) = (A@x)@Vw^T + rowsum(A) (x) Vb
// so h = [x|y] @ [Uw|Vw]^T + rs*Vb + Ub  with y = A@x  -> single K=1024 GEMM.

typedef _Float16 half8 __attribute__((ext_vector_type(8)));
typedef _Float16 half4 __attribute__((ext_vector_type(4)));
typedef float floatx4 __attribute__((ext_vector_type(4)));

#define NN 12
#define CH 512
#define NB 16384
#define M_ROWS (NB * NN)  // 196608

__device__ __forceinline__ float relu_f(float v) { return v > 0.f ? v : 0.f; }

// async global->LDS DMA, 16B per lane. LDS dest must be wave-uniform base;
// HW writes at base + lane*16 (linear). Our As/Bs layouts are lane-linear.
__device__ __forceinline__ void gload16(const void* g, void* l) {
    __builtin_amdgcn_global_load_lds(
        (__attribute__((address_space(1))) const unsigned int*)g,
        (__attribute__((address_space(3))) unsigned int*)l, 16, 0, 0);
}

// ---------------------------------------------------------------------------
// Kw: build concatenated fp16 weights Wcat[d][k], k<512 -> Uw[d][k], else Vw.
// Also zero the BN global accumulators (24 doubles).
// ---------------------------------------------------------------------------
__global__ __launch_bounds__(256) void kw_build(const float* __restrict__ Uw,
                                                const float* __restrict__ Vw,
                                                _Float16* __restrict__ Wcat,
                                                double* __restrict__ gAcc) {
    int e = blockIdx.x * 256 + threadIdx.x;  // 0 .. 524287
    int d = e >> 10, k = e & 1023;
    float v = (k < 512) ? Uw[d * 512 + k] : Vw[d * 512 + (k - 512)];
    Wcat[e] = (_Float16)v;
    if (blockIdx.x == 0 && threadIdx.x < 24) gAcc[threadIdx.x] = 0.0;
}

// ---------------------------------------------------------------------------
// K1: per-batch adjacency (exact double sim -> top-4 threshold -> normalized
// A), y = A@x, rs = rowsum(A). Writes x and y as fp16 (pathA: [row][1024]
// concat; pathB: y only [row][512]).
// Sim: symmetric -> 78 pairs; dot vectorized to ds_read_b128 (4 f64 accums).
// ---------------------------------------------------------------------------
__global__ __launch_bounds__(256) void k1_adj(const float* __restrict__ x,
                                              _Float16* __restrict__ Abuf,
                                              float* __restrict__ rs,
                                              int pathA) {
    __shared__ float xs[NN][CH + 4];   // stride 516: 16B-aligned rows; banks
                                       // shift 4/row -> worst 2-way (free)
    __shared__ double sim[NN][NN];
    __shared__ double thr[NN];
    __shared__ float Amat[NN][NN];
    __shared__ float dinv[NN];

    const int b = blockIdx.x, t = threadIdx.x;
    const float* xb = x + (size_t)b * NN * CH;

    for (int e = t; e < NN * CH / 4; e += 256) {  // 1536 float4
        int r = e >> 7, c4 = (e & 127) << 2;
        float4 v = ((const float4*)xb)[e];
        *(float4*)&xs[r][c4] = v;
    }
    __syncthreads();

    if (t < 78) {  // upper-triangle pairs i<=j, exact-product f64 accum
        int i = 0, rem = t;
        while (rem >= NN - i) { rem -= NN - i; i++; }
        const int j = i + rem;
        double a0 = 0.0, a1 = 0.0, a2 = 0.0, a3 = 0.0;
        for (int c = 0; c < CH; c += 4) {
            float4 va = *(const float4*)&xs[i][c];
            float4 vb = *(const float4*)&xs[j][c];
            a0 += (double)va.x * (double)vb.x;
            a1 += (double)va.y * (double)vb.y;
            a2 += (double)va.z * (double)vb.z;
            a3 += (double)va.w * (double)vb.w;
        }
        double acc = (a0 + a1) + (a2 + a3);
        sim[i][j] = acc;
        sim[j][i] = acc;
    }
    __syncthreads();

    if (t < 12) {  // 4th largest (with duplicates) via top-4 insertion
        double a = -1e300, b2 = -1e300, c2 = -1e300, d2 = -1e300;
        for (int j = 0; j < 12; j++) {
            double v = sim[t][j];
            if (v > a)       { d2 = c2; c2 = b2; b2 = a; a = v; }
            else if (v > b2) { d2 = c2; c2 = b2; b2 = v; }
            else if (v > c2) { d2 = c2; c2 = v; }
            else if (v > d2) { d2 = v; }
        }
        thr[t] = d2;
        int deg = 0;
        for (int j = 0; j < 12; j++) deg += (sim[t][j] >= d2);
        dinv[t] = 1.0f / sqrtf((float)deg);
    }
    __syncthreads();

    if (t < 144) {
        int i = t / 12, j = t % 12;
        Amat[i][j] = (sim[i][j] >= thr[i]) ? dinv[i] * dinv[j] : 0.0f;
    }
    __syncthreads();

    if (t < 12) {
        float s = 0.f;
        for (int j = 0; j < 12; j++) s += Amat[t][j];
        rs[b * NN + t] = s;
    }

    const size_t strideK = pathA ? 1024 : 512;
    const size_t yoff = pathA ? 512 : 0;
    for (int e = t; e < NN * CH / 4; e += 256) {  // 1536: 4 channels/thread
        int i = e >> 7, c4 = (e & 127) << 2;
        float ax = 0.f, ay = 0.f, az = 0.f, aw = 0.f;
#pragma unroll
        for (int j = 0; j < 12; j++) {
            const float a = Amat[i][j];
            float4 v = *(const float4*)&xs[j][c4];
            ax += a * v.x; ay += a * v.y; az += a * v.z; aw += a * v.w;
        }
        const size_t row = (size_t)b * NN + i;
        half4 hy;
        hy[0] = (_Float16)ax; hy[1] = (_Float16)ay;
        hy[2] = (_Float16)az; hy[3] = (_Float16)aw;
        *(half4*)(Abuf + row * strideK + yoff + c4) = hy;
        if (pathA) {
            float4 xv = *(const float4*)&xs[i][c4];
            half4 hx;
            hx[0] = (_Float16)xv.x; hx[1] = (_Float16)xv.y;
            hx[2] = (_Float16)xv.z; hx[3] = (_Float16)xv.w;
            *(half4*)(Abuf + row * 1024 + c4) = hx;
        }
    }
}

// ---------------------------------------------------------------------------
// K2: h = Acat @ Wcat^T + rs*Vb + Ub, written fp32 to d_out; fused BN partial
// sums (per n=m%12) -> global double atomics.
// Tile: BM=128 BN=128 BK=32, 4 waves, each 64x64 via 4x4 mfma 16x16x32 f16.
// Staging via global_load_lds width=16 (lane-linear LDS dest).
// Grid XCD-swizzled: the 4 nt-blocks sharing an A-panel land on one XCD.
// ---------------------------------------------------------------------------
__global__ __launch_bounds__(256) void k2_gemm(
    const _Float16* __restrict__ Abuf, const float* __restrict__ xf,
    const _Float16* __restrict__ Wcat, const float* __restrict__ rs,
    const float* __restrict__ Ub, const float* __restrict__ Vb,
    float* __restrict__ hout, double* __restrict__ gS1,
    double* __restrict__ gS2, int pathA) {
    __shared__ __align__(16) _Float16 As[128 * 32];
    __shared__ __align__(16) _Float16 Bs[128 * 32];
    __shared__ float bs1[12], bs2[12];

    const int t = threadIdx.x;
    // XCD-bijective remap (6144 blocks = 768/XCD): xcd = mt%8 so all 4
    // N-tiles of an A-panel share one L2; consecutive j -> temporal locality.
    const int bid = blockIdx.x;
    const int xcd = bid & 7, jj = bid >> 3;
    const int nt = jj & 3, mt = (jj >> 2) * 8 + xcd;
    const int m0 = mt * 128, n0 = nt * 128;
    const int lane = t & 63, wv = t >> 6;
    const int l15 = lane & 15, quad = lane >> 4;
    const int mwb = (wv & 1) * 64, nwb = (wv >> 1) * 64;
    const int srow = t >> 2, scol = (t & 3) * 8;  // staging: 16B/thread/pass

    // wave-uniform LDS bases for DMA: wave wv, pass p covers bytes
    // [p*4096 + wv*1024, +1024) = element offset p*2048 + wv*512
    _Float16* ldsA = As + wv * 512;
    _Float16* ldsB = Bs + wv * 512;

    floatx4 acc[4][4];
#pragma unroll
    for (int mi = 0; mi < 4; mi++)
#pragma unroll
        for (int ni = 0; ni < 4; ni++)
#pragma unroll
            for (int e = 0; e < 4; e++) acc[mi][ni][e] = 0.f;

    for (int kt = 0; kt < 32; kt++) {
        const int k0 = kt * 32;
        __syncthreads();
        if (pathA) {
#pragma unroll
            for (int pass = 0; pass < 2; pass++) {
                const int row = srow + pass * 64;
                const size_t grow = (size_t)(m0 + row);
                gload16(Abuf + grow * 1024 + k0 + scol, ldsA + pass * 2048);
                gload16(Wcat + (size_t)(n0 + row) * 1024 + k0 + scol,
                        ldsB + pass * 2048);
            }
        } else {
#pragma unroll
            for (int pass = 0; pass < 2; pass++) {
                const int row = srow + pass * 64;
                const size_t grow = (size_t)(m0 + row);
                if (k0 < 512) {  // A from fp32 x, converted (reg-staged)
                    const float* p = xf + grow * 512 + k0 + scol;
                    float4 f0 = *(const float4*)p;
                    float4 f1 = *(const float4*)(p + 4);
                    half8 va;
                    va[0] = (_Float16)f0.x; va[1] = (_Float16)f0.y;
                    va[2] = (_Float16)f0.z; va[3] = (_Float16)f0.w;
                    va[4] = (_Float16)f1.x; va[5] = (_Float16)f1.y;
                    va[6] = (_Float16)f1.z; va[7] = (_Float16)f1.w;
                    *(half8*)&As[row * 32 + scol] = va;
                } else {
                    gload16(Abuf + grow * 512 + (k0 - 512) + scol,
                            ldsA + pass * 2048);
                }
                gload16(Wcat + (size_t)(n0 + row) * 1024 + k0 + scol,
                        ldsB + pass * 2048);
            }
        }
        __syncthreads();  // drains vmcnt(0)+lgkmcnt(0): DMA landed

        half8 af[4], bfr[4];
#pragma unroll
        for (int mi = 0; mi < 4; mi++)
            af[mi] = *(half8*)&As[(mwb + mi * 16 + l15) * 32 + quad * 8];
#pragma unroll
        for (int ni = 0; ni < 4; ni++)
            bfr[ni] = *(half8*)&Bs[(nwb + ni * 16 + l15) * 32 + quad * 8];
#pragma unroll
        for (int mi = 0; mi < 4; mi++)
#pragma unroll
            for (int ni = 0; ni < 4; ni++)
                acc[mi][ni] = __builtin_amdgcn_mfma_f32_16x16x32_f16(
                    af[mi], bfr[ni], acc[mi][ni], 0, 0, 0);
    }

    // epilogue: bias, store h, BN partials
    if (t < 12) { bs1[t] = 0.f; bs2[t] = 0.f; }
    __syncthreads();
#pragma unroll
    for (int mi = 0; mi < 4; mi++) {
#pragma unroll
        for (int r = 0; r < 4; r++) {
            const int m = m0 + mwb + mi * 16 + quad * 4 + r;
            const float rsm = rs[m];
            float p1 = 0.f, p2 = 0.f;
#pragma unroll
            for (int ni = 0; ni < 4; ni++) {
                const int d = n0 + nwb + ni * 16 + l15;
                float h = acc[mi][ni][r] + rsm * Vb[d] + Ub[d];
                hout[(size_t)m * 512 + d] = h;
                p1 += h; p2 += h * h;
            }
            // reduce across the 16 lanes holding row m (same quad group)
            for (int off = 1; off < 16; off <<= 1) {
                p1 += __shfl_xor(p1, off, 16);
                p2 += __shfl_xor(p2, off, 16);
            }
            if (l15 == 0) {
                atomicAdd(&bs1[m % 12], p1);
                atomicAdd(&bs2[m % 12], p2);
            }
        }
    }
    __syncthreads();
    if (t < 12) {
        atomicAdd(&gS1[t], (double)bs1[t]);
        atomicAdd(&gS2[t], (double)bs2[t]);
    }
}

// ---------------------------------------------------------------------------
// K3: finalize BN: scale[n] = gamma*rsqrt(var+eps), shift[n] = beta - mean*scale
// ---------------------------------------------------------------------------
__global__ void k3_stats(const double* __restrict__ gS1,
                         const double* __restrict__ gS2,
                         const float* __restrict__ gamma,
                         const float* __restrict__ beta,
                         float* __restrict__ bnp) {
    int t = threadIdx.x;
    if (t < 12) {
        const double cnt = (double)NB * 512.0;
        double mean = gS1[t] / cnt;
        double var = gS2[t] / cnt - mean * mean;
        float inv = rsqrtf((float)var + 1e-5f);
        float scale = gamma[t] * inv;
        bnp[t] = scale;
        bnp[12 + t] = beta[t] - (float)mean * scale;
    }
}

// ---------------------------------------------------------------------------
// K4: out = relu(x + h*scale[n] + shift[n]), in place over d_out (h).
// ---------------------------------------------------------------------------
__global__ __launch_bounds__(256) void k4_final(const float* __restrict__ x,
                                                float* __restrict__ out,
                                                const float* __restrict__ bnp) {
    __shared__ float sc[12], sh[12];
    if (threadIdx.x < 12) {
        sc[threadIdx.x] = bnp[threadIdx.x];
        sh[threadIdx.x] = bnp[12 + threadIdx.x];
    }
    __syncthreads();
    const size_t n4 = (size_t)M_ROWS * 128;  // float4 count
    for (size_t i = (size_t)blockIdx.x * 256 + threadIdx.x; i < n4;
         i += (size_t)gridDim.x * 256) {
        int m = (int)(i >> 7);
        int n = m % 12;
        float4 h = ((const float4*)out)[i];
        float4 xv = ((const float4*)x)[i];
        float s = sc[n], b = sh[n];
        float4 r;
        r.x = relu_f(xv.x + h.x * s + b);
        r.y = relu_f(xv.y + h.y * s + b);
        r.z = relu_f(xv.z + h.z * s + b);
        r.w = relu_f(xv.w + h.w * s + b);
        ((float4*)out)[i] = r;
    }
}

// ---------------------------------------------------------------------------
extern "C" void kernel_launch(void* const* d_in, const int* in_sizes, int n_in,
                              void* d_out, int out_size, void* d_ws,
                              size_t ws_size, hipStream_t stream) {
    const float* x     = (const float*)d_in[0];
    const float* Uw    = (const float*)d_in[1];
    const float* Ub    = (const float*)d_in[2];
    const float* Vw    = (const float*)d_in[3];
    const float* Vb    = (const float*)d_in[4];
    const float* gamma = (const float*)d_in[5];
    const float* beta  = (const float*)d_in[6];
    float* out = (float*)d_out;

    const size_t szA  = (size_t)M_ROWS * 1024 * 2;  // 402.7 MB fp16 [x|y]
    const size_t szB  = (size_t)M_ROWS * 512 * 2;   // 201.3 MB fp16 y only
    const size_t szW  = (size_t)512 * 1024 * 2;     // 1 MB
    const size_t szrs = (size_t)M_ROWS * 4;         // 0.79 MB
    const size_t needA = szA + szW + szrs + 24 * 8 + 24 * 4;
    const int pathA = (ws_size >= needA) ? 1 : 0;   // host-constant -> capture-safe

    char* w = (char*)d_ws;
    _Float16* Abuf = (_Float16*)w;
    const size_t big = pathA ? szA : szB;
    _Float16* Wcat = (_Float16*)(w + big);
    float* rs      = (float*)(w + big + szW);
    double* gS1    = (double*)(w + big + szW + szrs);
    double* gS2    = gS1 + 12;
    float* bnp     = (float*)(gS2 + 12);

    kw_build<<<2048, 256, 0, stream>>>(Uw, Vw, Wcat, gS1);
    k1_adj<<<NB, 256, 0, stream>>>(x, Abuf, rs, pathA);
    k2_gemm<<<(M_ROWS / 128) * 4, 256, 0, stream>>>(Abuf, x, Wcat, rs, Ub, Vb,
                                                    out, gS1, gS2, pathA);
    k3_stats<<<1, 64, 0, stream>>>(gS1, gS2, gamma, beta, bnp);
    k4_final<<<4096, 256, 0, stream>>>(x, out, bnp);
}

// Round 2
// 1235.138 us; speedup vs baseline: 1.2403x; 1.1440x over previous
//
#include <hip/hip_runtime.h>
#include <hip/hip_fp16.h>

// GNN_6253472383532: dynamic top-k GCN block + BN + relu residual.
// b=16384, n=12, c=512, K(neighbors)=4.
//
// Math rewrite: agg = A @ (x@Vw^T + Vb) = (A@x)@Vw^T + rowsum(A) (x) Vb
// so h = [x|y] @ [Uw|Vw]^T + rs*Vb + Ub  with y = A@x  -> single K=1024 GEMM.

typedef _Float16 half8 __attribute__((ext_vector_type(8)));
typedef _Float16 half4 __attribute__((ext_vector_type(4)));
typedef float floatx4 __attribute__((ext_vector_type(4)));

#define NN 12
#define CH 512
#define NB 16384
#define M_ROWS (NB * NN)  // 196608

__device__ __forceinline__ float relu_f(float v) { return v > 0.f ? v : 0.f; }

// async global->LDS DMA, 16B per lane. LDS dest must be wave-uniform base;
// HW writes at base + lane*16 (linear). Global source addr is per-lane.
__device__ __forceinline__ void gload16(const void* g, void* l) {
    __builtin_amdgcn_global_load_lds(
        (__attribute__((address_space(1))) const unsigned int*)g,
        (__attribute__((address_space(3))) unsigned int*)l, 16, 0, 0);
}

// ---------------------------------------------------------------------------
// Kw: build concatenated fp16 weights Wcat[d][k], k<512 -> Uw[d][k], else Vw.
// Also zero the BN global accumulators (24 doubles).
// ---------------------------------------------------------------------------
__global__ __launch_bounds__(256) void kw_build(const float* __restrict__ Uw,
                                                const float* __restrict__ Vw,
                                                _Float16* __restrict__ Wcat,
                                                double* __restrict__ gAcc) {
    int e = blockIdx.x * 256 + threadIdx.x;  // 0 .. 524287
    int d = e >> 10, k = e & 1023;
    float v = (k < 512) ? Uw[d * 512 + k] : Vw[d * 512 + (k - 512)];
    Wcat[e] = (_Float16)v;
    if (blockIdx.x == 0 && threadIdx.x < 24) gAcc[threadIdx.x] = 0.0;
}

// ---------------------------------------------------------------------------
// K1: per-batch adjacency (exact double sim -> top-4 threshold -> normalized
// A), y = A@x, rs = rowsum(A). Writes x and y as fp16 (pathA: [row][1024]
// concat; pathB: y only [row][512]).
// Sim: symmetric 78 pairs, each split over 3 channel ranges (234 threads).
// ---------------------------------------------------------------------------
__global__ __launch_bounds__(256) void k1_adj(const float* __restrict__ x,
                                              _Float16* __restrict__ Abuf,
                                              float* __restrict__ rs,
                                              int pathA) {
    __shared__ float xs[NN][CH + 4];   // stride 516: 16B-aligned rows
    __shared__ double psum[78][3];
    __shared__ double sim[NN][NN];
    __shared__ double thr[NN];
    __shared__ float Amat[NN][NN];
    __shared__ float dinv[NN];

    const int b = blockIdx.x, t = threadIdx.x;
    const float* xb = x + (size_t)b * NN * CH;

    for (int e = t; e < NN * CH / 4; e += 256) {  // 1536 float4
        int r = e >> 7, c4 = (e & 127) << 2;
        float4 v = ((const float4*)xb)[e];
        *(float4*)&xs[r][c4] = v;
    }
    __syncthreads();

    if (t < 234) {  // pair p = t/3, channel-range s = t%3
        const int p = t / 3, s = t - p * 3;
        int i = 0, rem = p;
        while (rem >= NN - i) { rem -= NN - i; i++; }
        const int j = i + rem;
        const int c0 = (s == 0) ? 0 : (s == 1 ? 176 : 352);
        const int c1 = (s == 0) ? 176 : (s == 1 ? 352 : 512);
        double a0 = 0.0, a1 = 0.0, a2 = 0.0, a3 = 0.0;
        for (int c = c0; c < c1; c += 4) {
            float4 va = *(const float4*)&xs[i][c];
            float4 vb = *(const float4*)&xs[j][c];
            a0 += (double)va.x * (double)vb.x;
            a1 += (double)va.y * (double)vb.y;
            a2 += (double)va.z * (double)vb.z;
            a3 += (double)va.w * (double)vb.w;
        }
        psum[p][s] = (a0 + a1) + (a2 + a3);
    }
    __syncthreads();

    if (t < 78) {
        int i = 0, rem = t;
        while (rem >= NN - i) { rem -= NN - i; i++; }
        const int j = i + rem;
        double acc = (psum[t][0] + psum[t][1]) + psum[t][2];
        sim[i][j] = acc;
        sim[j][i] = acc;
    }
    __syncthreads();

    if (t < 12) {  // 4th largest (with duplicates) via top-4 insertion
        double a = -1e300, b2 = -1e300, c2 = -1e300, d2 = -1e300;
        for (int j = 0; j < 12; j++) {
            double v = sim[t][j];
            if (v > a)       { d2 = c2; c2 = b2; b2 = a; a = v; }
            else if (v > b2) { d2 = c2; c2 = b2; b2 = v; }
            else if (v > c2) { d2 = c2; c2 = v; }
            else if (v > d2) { d2 = v; }
        }
        thr[t] = d2;
        int deg = 0;
        for (int j = 0; j < 12; j++) deg += (sim[t][j] >= d2);
        dinv[t] = 1.0f / sqrtf((float)deg);
    }
    __syncthreads();

    if (t < 144) {
        int i = t / 12, j = t % 12;
        Amat[i][j] = (sim[i][j] >= thr[i]) ? dinv[i] * dinv[j] : 0.0f;
    }
    __syncthreads();

    if (t < 12) {
        float s = 0.f;
        for (int j = 0; j < 12; j++) s += Amat[t][j];
        rs[b * NN + t] = s;
    }

    const size_t strideK = pathA ? 1024 : 512;
    const size_t yoff = pathA ? 512 : 0;
    for (int e = t; e < NN * CH / 4; e += 256) {  // 1536: 4 channels/thread
        int i = e >> 7, c4 = (e & 127) << 2;
        float ax = 0.f, ay = 0.f, az = 0.f, aw = 0.f;
#pragma unroll
        for (int j = 0; j < 12; j++) {
            const float a = Amat[i][j];
            float4 v = *(const float4*)&xs[j][c4];
            ax += a * v.x; ay += a * v.y; az += a * v.z; aw += a * v.w;
        }
        const size_t row = (size_t)b * NN + i;
        half4 hy;
        hy[0] = (_Float16)ax; hy[1] = (_Float16)ay;
        hy[2] = (_Float16)az; hy[3] = (_Float16)aw;
        *(half4*)(Abuf + row * strideK + yoff + c4) = hy;
        if (pathA) {
            float4 xv = *(const float4*)&xs[i][c4];
            half4 hx;
            hx[0] = (_Float16)xv.x; hx[1] = (_Float16)xv.y;
            hx[2] = (_Float16)xv.z; hx[3] = (_Float16)xv.w;
            *(half4*)(Abuf + row * 1024 + c4) = hx;
        }
    }
}

// ---------------------------------------------------------------------------
// K2: h = Acat @ Wcat^T + rs*Vb + Ub; fused BN partial sums -> double atomics.
// Tile: BM=128 BN=128 BK=32, 4 waves, each 64x64 via 4x4 mfma 16x16x32 f16.
// 2-phase double-buffer: stage(kt+1) issued BEFORE compute(kt); single
// barrier/iter (its implicit vmcnt(0) finds loads already landed).
// LDS 16B-slot XOR swizzle (slot q ^= (row>>1)&3): gload_lds dest stays
// linear, global SOURCE pre-swizzled, ds_read col swizzled (rule 21).
// ---------------------------------------------------------------------------
__global__ __launch_bounds__(256) void k2_gemm(
    const _Float16* __restrict__ Abuf, const float* __restrict__ xf,
    const _Float16* __restrict__ Wcat, const float* __restrict__ rs,
    const float* __restrict__ Ub, const float* __restrict__ Vb,
    float* __restrict__ hout, _Float16* __restrict__ hout16,
    double* __restrict__ gS1, double* __restrict__ gS2, int pathA, int hpath) {
    __shared__ __align__(16) _Float16 As[2][128 * 32];
    __shared__ __align__(16) _Float16 Bs[2][128 * 32];
    __shared__ float bs1[12], bs2[12];

    const int t = threadIdx.x;
    // XCD-bijective remap (6144 blocks = 768/XCD): xcd = mt%8 so all 4
    // N-tiles of an A-panel share one L2.
    const int bid = blockIdx.x;
    const int xcd = bid & 7, jj = bid >> 3;
    const int nt = jj & 3, mt = (jj >> 2) * 8 + xcd;
    const int m0 = mt * 128, n0 = nt * 128;
    const int lane = t & 63, wv = t >> 6;
    const int l15 = lane & 15, quad = lane >> 4;
    const int mwb = (wv & 1) * 64, nwb = (wv >> 1) * 64;
    // staging geometry: thread covers row srow(+64), 16B slot qs of that row.
    const int srow = t >> 2, qs = t & 3;
    const int fsw = (srow >> 1) & 3;       // same for srow and srow+64
    const int scol = (qs ^ fsw) * 8;       // swizzled source column (elems)

    floatx4 acc[4][4];
#pragma unroll
    for (int mi = 0; mi < 4; mi++)
#pragma unroll
        for (int ni = 0; ni < 4; ni++)
#pragma unroll
            for (int e = 0; e < 4; e++) acc[mi][ni][e] = 0.f;

    auto stage = [&](int buf, int kt) {
        const int k0 = kt * 32;
#pragma unroll
        for (int pass = 0; pass < 2; pass++) {
            const int row = srow + pass * 64;
            const size_t grow = (size_t)(m0 + row);
            _Float16* la = &As[buf][pass * 2048 + wv * 512];  // wave-uniform
            _Float16* lb = &Bs[buf][pass * 2048 + wv * 512];
            if (pathA) {
                gload16(Abuf + grow * 1024 + k0 + scol, la);
            } else if (k0 < 512) {  // A from fp32 x, reg-staged + swz write
                const float* p = xf + grow * 512 + k0 + scol;
                float4 f0 = *(const float4*)p;
                float4 f1 = *(const float4*)(p + 4);
                half8 va;
                va[0] = (_Float16)f0.x; va[1] = (_Float16)f0.y;
                va[2] = (_Float16)f0.z; va[3] = (_Float16)f0.w;
                va[4] = (_Float16)f1.x; va[5] = (_Float16)f1.y;
                va[6] = (_Float16)f1.z; va[7] = (_Float16)f1.w;
                *(half8*)&As[buf][row * 32 + qs * 8] = va;
            } else {
                gload16(Abuf + grow * 512 + (k0 - 512) + scol, la);
            }
            gload16(Wcat + (size_t)(n0 + row) * 1024 + k0 + scol, lb);
        }
    };

    stage(0, 0);
    __syncthreads();  // drain: buf0 ready

    // fragment-read column, swizzled: global slot quad of row r lives at
    // LDS slot quad ^ ((r>>1)&3); r = *+l15 -> (r>>1)&3 = (l15>>1)&3.
    const int rcol = (quad ^ ((l15 >> 1) & 3)) * 8;

    int cur = 0;
    for (int kt = 0; kt < 32; kt++) {
        if (kt < 31) stage(cur ^ 1, kt + 1);  // async, lands during compute

        half8 af[4], bfr[4];
#pragma unroll
        for (int mi = 0; mi < 4; mi++)
            af[mi] = *(half8*)&As[cur][(mwb + mi * 16 + l15) * 32 + rcol];
#pragma unroll
        for (int ni = 0; ni < 4; ni++)
            bfr[ni] = *(half8*)&Bs[cur][(nwb + ni * 16 + l15) * 32 + rcol];
#pragma unroll
        for (int mi = 0; mi < 4; mi++)
#pragma unroll
            for (int ni = 0; ni < 4; ni++)
                acc[mi][ni] = __builtin_amdgcn_mfma_f32_16x16x32_f16(
                    af[mi], bfr[ni], acc[mi][ni], 0, 0, 0);

        __syncthreads();  // all reads of cur done + next buf landed
        cur ^= 1;
    }

    // epilogue: bias, store h (fp16 if hpath), BN partials
    if (t < 12) { bs1[t] = 0.f; bs2[t] = 0.f; }
    __syncthreads();
#pragma unroll
    for (int mi = 0; mi < 4; mi++) {
#pragma unroll
        for (int r = 0; r < 4; r++) {
            const int m = m0 + mwb + mi * 16 + quad * 4 + r;
            const float rsm = rs[m];
            float p1 = 0.f, p2 = 0.f;
#pragma unroll
            for (int ni = 0; ni < 4; ni++) {
                const int d = n0 + nwb + ni * 16 + l15;
                float h = acc[mi][ni][r] + rsm * Vb[d] + Ub[d];
                if (hpath) hout16[(size_t)m * 512 + d] = (_Float16)h;
                else       hout[(size_t)m * 512 + d] = h;
                p1 += h; p2 += h * h;
            }
            for (int off = 1; off < 16; off <<= 1) {
                p1 += __shfl_xor(p1, off, 16);
                p2 += __shfl_xor(p2, off, 16);
            }
            if (l15 == 0) {
                atomicAdd(&bs1[m % 12], p1);
                atomicAdd(&bs2[m % 12], p2);
            }
        }
    }
    __syncthreads();
    if (t < 12) {
        atomicAdd(&gS1[t], (double)bs1[t]);
        atomicAdd(&gS2[t], (double)bs2[t]);
    }
}

// ---------------------------------------------------------------------------
// K3: finalize BN: scale[n] = gamma*rsqrt(var+eps), shift[n] = beta - mean*scale
// ---------------------------------------------------------------------------
__global__ void k3_stats(const double* __restrict__ gS1,
                         const double* __restrict__ gS2,
                         const float* __restrict__ gamma,
                         const float* __restrict__ beta,
                         float* __restrict__ bnp) {
    int t = threadIdx.x;
    if (t < 12) {
        const double cnt = (double)NB * 512.0;
        double mean = gS1[t] / cnt;
        double var = gS2[t] / cnt - mean * mean;
        float inv = rsqrtf((float)var + 1e-5f);
        float scale = gamma[t] * inv;
        bnp[t] = scale;
        bnp[12 + t] = beta[t] - (float)mean * scale;
    }
}

// ---------------------------------------------------------------------------
// K4: out = relu(x + h*scale[n] + shift[n]); h from fp16 buf (hpath) or
// in place over d_out.
// ---------------------------------------------------------------------------
__global__ __launch_bounds__(256) void k4_final(const float* __restrict__ x,
                                                float* __restrict__ out,
                                                const _Float16* __restrict__ h16,
                                                const float* __restrict__ bnp,
                                                int hpath) {
    __shared__ float sc[12], sh[12];
    if (threadIdx.x < 12) {
        sc[threadIdx.x] = bnp[threadIdx.x];
        sh[threadIdx.x] = bnp[12 + threadIdx.x];
    }
    __syncthreads();
    const size_t n4 = (size_t)M_ROWS * 128;  // float4 count
    for (size_t i = (size_t)blockIdx.x * 256 + threadIdx.x; i < n4;
         i += (size_t)gridDim.x * 256) {
        int m = (int)(i >> 7);
        int n = m % 12;
        float4 h;
        if (hpath) {
            half4 hv = *(const half4*)(h16 + i * 4);
            h.x = (float)hv[0]; h.y = (float)hv[1];
            h.z = (float)hv[2]; h.w = (float)hv[3];
        } else {
            h = ((const float4*)out)[i];
        }
        float4 xv = ((const float4*)x)[i];
        float s = sc[n], b = sh[n];
        float4 r;
        r.x = relu_f(xv.x + h.x * s + b);
        r.y = relu_f(xv.y + h.y * s + b);
        r.z = relu_f(xv.z + h.z * s + b);
        r.w = relu_f(xv.w + h.w * s + b);
        ((float4*)out)[i] = r;
    }
}

// ---------------------------------------------------------------------------
extern "C" void kernel_launch(void* const* d_in, const int* in_sizes, int n_in,
                              void* d_out, int out_size, void* d_ws,
                              size_t ws_size, hipStream_t stream) {
    const float* x     = (const float*)d_in[0];
    const float* Uw    = (const float*)d_in[1];
    const float* Ub    = (const float*)d_in[2];
    const float* Vw    = (const float*)d_in[3];
    const float* Vb    = (const float*)d_in[4];
    const float* gamma = (const float*)d_in[5];
    const float* beta  = (const float*)d_in[6];
    float* out = (float*)d_out;

    const size_t szA  = (size_t)M_ROWS * 1024 * 2;  // 402.7 MB fp16 [x|y]
    const size_t szB  = (size_t)M_ROWS * 512 * 2;   // 201.3 MB fp16 y only
    const size_t szW  = (size_t)512 * 1024 * 2;     // 1 MB
    const size_t szrs = (size_t)M_ROWS * 4;         // 0.79 MB
    const size_t szH  = (size_t)M_ROWS * 512 * 2;   // 201.3 MB fp16 h
    const size_t needA = szA + szW + szrs + 24 * 8 + 24 * 4;
    const int pathA = (ws_size >= needA) ? 1 : 0;        // host-const: capture-safe
    const int hpath = (pathA && ws_size >= needA + szH) ? 1 : 0;

    char* w = (char*)d_ws;
    _Float16* Abuf = (_Float16*)w;
    const size_t big = pathA ? szA : szB;
    _Float16* Wcat = (_Float16*)(w + big);
    float* rs      = (float*)(w + big + szW);
    double* gS1    = (double*)(w + big + szW + szrs);
    double* gS2    = gS1 + 12;
    float* bnp     = (float*)(gS2 + 12);
    _Float16* Hbuf = (_Float16*)(w + needA);  // valid iff hpath

    kw_build<<<2048, 256, 0, stream>>>(Uw, Vw, Wcat, gS1);
    k1_adj<<<NB, 256, 0, stream>>>(x, Abuf, rs, pathA);
    k2_gemm<<<(M_ROWS / 128) * 4, 256, 0, stream>>>(Abuf, x, Wcat, rs, Ub, Vb,
                                                    out, Hbuf, gS1, gS2, pathA,
                                                    hpath);
    k3_stats<<<1, 64, 0, stream>>>(gS1, gS2, gamma, beta, bnp);
    k4_final<<<4096, 256, 0, stream>>>(x, out, Hbuf, bnp, hpath);
}